// Round 1
// baseline (60614.990 us; speedup 1.0000x reference)
//
#include <hip/hip_runtime.h>
#include <math.h>

__device__ __forceinline__ int ufl(int v) { return __builtin_amdgcn_readfirstlane(v); }

// ---------------------------------------------------------------------------
// Direct conv, k=5 pad=2 stride S, weights [COUT][CIN][5][5], NCHW tensors.
// Block: 256 threads. PX = HOUT*WOUT (64 or 256). Input chunk staged in LDS
// with a 2-cell zero halo so the tap loop has no boundary branches.
// ---------------------------------------------------------------------------
template<int CIN, int COUT, int HIN, int WIN, int S, int CI_CHUNK, int CO_PER_BLOCK>
__global__ __launch_bounds__(256)
void conv5k(const float* __restrict__ in, const float* __restrict__ wt,
            const float* __restrict__ bias, float* __restrict__ out)
{
    constexpr int HOUT = HIN / S, WOUT = WIN / S;
    constexpr int PX   = HOUT * WOUT;
    constexpr int NCOG = (PX >= 256) ? 1 : (256 / PX);
    constexpr int CO_ITERS = CO_PER_BLOCK / NCOG;
    constexpr int HT = HIN + 4, WT = WIN + 4;
    constexpr int NCHUNK = CIN / CI_CHUNK;
    constexpr int TILE = CI_CHUNK * HT * WT;

    __shared__ float lds[TILE];

    const int b = blockIdx.x;
    const int co_base = blockIdx.y * CO_PER_BLOCK;
    const int tid = threadIdx.x;
    const int px  = (PX >= 256) ? tid : (tid & (PX - 1));
    const int cog = (PX >= 256) ? 0   : (tid / PX);
    const int oy = px / WOUT, ox = px % WOUT;

    float acc[CO_ITERS];
#pragma unroll
    for (int i = 0; i < CO_ITERS; ++i) acc[i] = 0.f;

    const float* inb = in + (size_t)b * CIN * HIN * WIN;

#pragma unroll 1
    for (int ch = 0; ch < NCHUNK; ++ch) {
        if (ch) __syncthreads();
        for (int idx = tid; idx < TILE; idx += 256) lds[idx] = 0.f;
        __syncthreads();
        for (int idx = tid; idx < CI_CHUNK * HIN * WIN; idx += 256) {
            int ci = idx / (HIN * WIN);
            int r  = idx - ci * (HIN * WIN);
            int iy = r / WIN, ix = r - iy * WIN;
            lds[ci * (HT * WT) + (iy + 2) * WT + (ix + 2)] =
                inb[(size_t)(ch * CI_CHUNK + ci) * (HIN * WIN) + r];
        }
        __syncthreads();

#pragma unroll 1
        for (int ci = 0; ci < CI_CHUNK; ++ci) {
            float v[25];
            const float* l = &lds[ci * (HT * WT) + (oy * S) * WT + (ox * S)];
#pragma unroll
            for (int ky = 0; ky < 5; ++ky)
#pragma unroll
                for (int kx = 0; kx < 5; ++kx)
                    v[ky * 5 + kx] = l[ky * WT + kx];
#pragma unroll
            for (int i = 0; i < CO_ITERS; ++i) {
                const int co = co_base + cog * CO_ITERS + i;
                const float* wp = wt + (size_t)ufl((co * CIN + ch * CI_CHUNK + ci) * 25);
#pragma unroll
                for (int t = 0; t < 25; ++t) acc[i] = fmaf(wp[t], v[t], acc[i]);
            }
        }
    }

#pragma unroll
    for (int i = 0; i < CO_ITERS; ++i) {
        const int co = co_base + cog * CO_ITERS + i;
        out[((size_t)b * COUT + co) * PX + px] = acc[i] + bias[co];
    }
}

// ---------------------------------------------------------------------------
// ConvTranspose2d k=5 s=1 p=2 (deconv1). Weights [CIN][COUT][5][5].
// Gather form: out[oy,ox] += w[ci,co,ky,kx] * in[oy+2-ky, ox+2-kx], halo=2.
// ---------------------------------------------------------------------------
template<int CIN, int COUT, int HW, int CI_CHUNK, int CO_PER_BLOCK>
__global__ __launch_bounds__(256)
void deconv1k(const float* __restrict__ in, const float* __restrict__ wt,
              const float* __restrict__ bias, float* __restrict__ out)
{
    constexpr int PX = HW * HW;           // 64
    constexpr int NCOG = 256 / PX;        // 4
    constexpr int CO_ITERS = CO_PER_BLOCK / NCOG;
    constexpr int HT = HW + 4, WT = HW + 4;
    constexpr int NCHUNK = CIN / CI_CHUNK;
    constexpr int TILE = CI_CHUNK * HT * WT;

    __shared__ float lds[TILE];

    const int b = blockIdx.x;
    const int co_base = blockIdx.y * CO_PER_BLOCK;
    const int tid = threadIdx.x;
    const int px  = tid & (PX - 1);
    const int cog = tid / PX;
    const int oy = px / HW, ox = px % HW;

    float acc[CO_ITERS];
#pragma unroll
    for (int i = 0; i < CO_ITERS; ++i) acc[i] = 0.f;

    const float* inb = in + (size_t)b * CIN * HW * HW;

#pragma unroll 1
    for (int ch = 0; ch < NCHUNK; ++ch) {
        if (ch) __syncthreads();
        for (int idx = tid; idx < TILE; idx += 256) lds[idx] = 0.f;
        __syncthreads();
        for (int idx = tid; idx < CI_CHUNK * HW * HW; idx += 256) {
            int ci = idx / (HW * HW);
            int r  = idx - ci * (HW * HW);
            int iy = r / HW, ix = r - iy * HW;
            lds[ci * (HT * WT) + (iy + 2) * WT + (ix + 2)] =
                inb[(size_t)(ch * CI_CHUNK + ci) * (HW * HW) + r];
        }
        __syncthreads();

#pragma unroll 1
        for (int ci = 0; ci < CI_CHUNK; ++ci) {
            float v[25];
            const float* l = &lds[ci * (HT * WT) + (oy + 4) * WT + (ox + 4)];
#pragma unroll
            for (int ky = 0; ky < 5; ++ky)
#pragma unroll
                for (int kx = 0; kx < 5; ++kx)
                    v[ky * 5 + kx] = l[-(ky * WT) - kx];
#pragma unroll
            for (int i = 0; i < CO_ITERS; ++i) {
                const int co = co_base + cog * CO_ITERS + i;
                const float* wp = wt + (size_t)ufl((((ch * CI_CHUNK + ci) * COUT) + co) * 25);
#pragma unroll
                for (int t = 0; t < 25; ++t) acc[i] = fmaf(wp[t], v[t], acc[i]);
            }
        }
    }

#pragma unroll
    for (int i = 0; i < CO_ITERS; ++i) {
        const int co = co_base + cog * CO_ITERS + i;
        out[((size_t)b * COUT + co) * PX + px] = acc[i] + bias[co];
    }
}

// ---------------------------------------------------------------------------
// ConvTranspose2d k=5 s=2 p=2 outpad=1 (deconv2/deconv3). Weights [CIN][COUT][5][5].
// Gather: out[oy] += w[ci,co,ky,.] * in[(oy+2-ky)/2] iff (oy+2-ky) even.
// Pixels enumerated parity-major so each wave has uniform (qy,qx):
// only valid taps (9/6/6/4 by parity) are computed. Halo = 1.
// ---------------------------------------------------------------------------
template<int CIN, int COUT, int HIN, int WIN, int CI_CHUNK, int CO_PER_BLOCK, bool CLIP>
__global__ __launch_bounds__(256)
void deconv2k(const float* __restrict__ in, const float* __restrict__ wt,
              const float* __restrict__ bias, float* __restrict__ out)
{
    constexpr int HOUT = HIN * 2, WOUT = WIN * 2;
    constexpr int PX = HOUT * WOUT;
    constexpr int HT = HIN + 2, WT = WIN + 2;
    constexpr int NCHUNK = CIN / CI_CHUNK;
    constexpr int TILE = CI_CHUNK * HT * WT;
    constexpr int WH = WOUT / 2;
    constexpr int SUB = (HOUT / 2) * WH;              // 64 or 256
    constexpr int QPT = (SUB == 64) ? 1 : (SUB / 64); // quads per thread
    constexpr int CO_ITERS = CO_PER_BLOCK;

    __shared__ float lds[TILE];
    const int b = blockIdx.x;
    const int co_base = blockIdx.y * CO_PER_BLOCK;
    const int tid = threadIdx.x;

    float acc[QPT][CO_ITERS];
#pragma unroll
    for (int q = 0; q < QPT; ++q)
#pragma unroll
        for (int i = 0; i < CO_ITERS; ++i) acc[q][i] = 0.f;

    const float* inb = in + (size_t)b * CIN * HIN * WIN;

#pragma unroll 1
    for (int ch = 0; ch < NCHUNK; ++ch) {
        if (ch) __syncthreads();
        for (int idx = tid; idx < TILE; idx += 256) lds[idx] = 0.f;
        __syncthreads();
        for (int idx = tid; idx < CI_CHUNK * HIN * WIN; idx += 256) {
            int ci = idx / (HIN * WIN);
            int r  = idx - ci * (HIN * WIN);
            int iy = r / WIN, ix = r - iy * WIN;
            lds[ci * (HT * WT) + (iy + 1) * WT + (ix + 1)] =
                inb[(size_t)(ch * CI_CHUNK + ci) * (HIN * WIN) + r];
        }
        __syncthreads();

#pragma unroll 1
        for (int q = 0; q < QPT; ++q) {
            int quad, sub;
            if constexpr (QPT == 1) { quad = tid >> 6; sub = tid & 63; }
            else                    { quad = q;        sub = tid;      }
            const int qy = quad >> 1, qx = quad & 1;
            const int sy = sub / WH, sx = sub % WH;
            const int nty = 3 - qy, ntx = 3 - qx;

#pragma unroll 1
            for (int ci = 0; ci < CI_CHUNK; ++ci) {
                float v[9] = {0.f,0.f,0.f,0.f,0.f,0.f,0.f,0.f,0.f};
                const float* l = &lds[ci * (HT * WT) + (sy + 2) * WT + (sx + 2)];
#pragma unroll
                for (int ty = 0; ty < 3; ++ty)
#pragma unroll
                    for (int tx = 0; tx < 3; ++tx)
                        if (ty < nty && tx < ntx)
                            v[ty * 3 + tx] = l[-(ty * WT) - tx];
#pragma unroll
                for (int i = 0; i < CO_ITERS; ++i) {
                    const int co = co_base + i;
                    const int wo = ufl(((ch * CI_CHUNK + ci) * COUT + co) * 25 + qy * 5 + qx);
#pragma unroll
                    for (int ty = 0; ty < 3; ++ty)
#pragma unroll
                        for (int tx = 0; tx < 3; ++tx)
                            if (ty < nty && tx < ntx)
                                acc[q][i] = fmaf(wt[wo + 10 * ty + 2 * tx], v[ty * 3 + tx], acc[q][i]);
                }
            }
        }
    }

#pragma unroll
    for (int q = 0; q < QPT; ++q) {
        int quad, sub;
        if constexpr (QPT == 1) { quad = tid >> 6; sub = tid & 63; }
        else                    { quad = q;        sub = tid;      }
        const int qy = quad >> 1, qx = quad & 1;
        const int sy = sub / WH, sx = sub % WH;
        const int oy = sy * 2 + qy, ox = sx * 2 + qx;
#pragma unroll
        for (int i = 0; i < CO_ITERS; ++i) {
            const int co = co_base + i;
            float r = acc[q][i] + bias[co];
            if (CLIP) r = fminf(fmaxf(r, 0.f), 1.f);
            out[((size_t)b * COUT + co) * PX + oy * WOUT + ox] = r;
        }
    }
}

// ---------------------------------------------------------------------------
// GDN (in-place): out[b,o,p] = x[b,o,p] * rsqrt/sqrt( beta[o] + sum_c gamma[o,c] x[b,c,p]^2 )
// Block: 256 threads = 64 px * 4 wave-groups; each thread owns 64 output chans.
// x tile (256ch x 64px) staged in LDS; gamma rows via scalar loads.
// ---------------------------------------------------------------------------
template<int P_IMG, bool INVERSE>
__global__ __launch_bounds__(256)
void gdnk(float* __restrict__ x, const float* __restrict__ beta,
          const float* __restrict__ gamma)
{
    __shared__ float xs[256 * 64];
    const int b  = blockIdx.x;
    const int pb = blockIdx.y * 64;
    const int tid = threadIdx.x;
    const int px = tid & 63;
    const int og = tid >> 6;

    float* xb = x + (size_t)b * 256 * P_IMG + pb;

#pragma unroll 4
    for (int k = 0; k < 64; ++k) {
        const int c = og + 4 * k;
        xs[c * 64 + px] = xb[(size_t)c * P_IMG + px];
    }
    __syncthreads();

    const int co0 = og * 64;
    float acc[64];
#pragma unroll
    for (int k = 0; k < 64; ++k) acc[k] = beta[ufl(co0 + k)];

#pragma unroll 1
    for (int cc = 0; cc < 32; ++cc) {
        float xv[8];
#pragma unroll
        for (int u = 0; u < 8; ++u) {
            float t = xs[(cc * 8 + u) * 64 + px];
            xv[u] = t * t;
        }
#pragma unroll
        for (int k = 0; k < 64; ++k) {
            const float* g = gamma + (size_t)ufl((co0 + k) * 256 + cc * 8);
#pragma unroll
            for (int u = 0; u < 8; ++u) acc[k] = fmaf(g[u], xv[u], acc[k]);
        }
    }

#pragma unroll 4
    for (int k = 0; k < 64; ++k) {
        const float n = acc[k];
        const float r = INVERSE ? sqrtf(n) : rsqrtf(n);
        xb[(size_t)(co0 + k) * P_IMG + px] = xs[(co0 + k) * 64 + px] * r;
    }
}

// ---------------------------------------------------------------------------
// Fused context model: per (b, c) wave of 64 lanes over the 64 spatial slots.
//   w_res   = y - H_tril y           (strictly-lower masked matvec, shfl loop)
//   w_hat   = w_res + noise
//   lik     = Gaussian CDF difference (erfc), scale lower-bounded at 0.11
//   y_hat   = (I - H_tril)^{-1} w_hat  (forward substitution via shfl recurrence)
// y updated in place; H[c] staged in LDS with stride 65 (conflict-free rows).
// ---------------------------------------------------------------------------
__global__ __launch_bounds__(256)
void trik(float* __restrict__ y, const float* __restrict__ noise,
          const float* __restrict__ H, const float* __restrict__ mean,
          const float* __restrict__ scale, float* __restrict__ lik)
{
    __shared__ float h[64 * 65];
    const int c   = blockIdx.x;
    const int bt  = blockIdx.y;
    const int tid = threadIdx.x;
    const int lane = tid & 63;
    const int wv   = tid >> 6;

    const float* Hc = H + (size_t)c * 4096;
    for (int idx = tid; idx < 4096; idx += 256) {
        const int i = idx >> 6, j = idx & 63;
        h[i * 65 + j] = Hc[idx];
    }
    __syncthreads();

    const int b = bt * 4 + wv;
    const size_t base = ((size_t)b * 320 + c) * 64 + lane;
    const float* hrow = &h[lane * 65];

    const float yv = y[base];
    float ws = 0.f;
#pragma unroll 8
    for (int j = 0; j < 64; ++j) {
        const float yj = __shfl(yv, j, 64);
        const float hv = (j < lane) ? hrow[j] : 0.f;
        ws = fmaf(hv, yj, ws);
    }
    const float wh = yv - ws + noise[base];

    const float mn = mean[c * 64 + lane];
    const float sc = fmaxf(scale[c * 64 + lane], 0.11f);
    const float vv = fabsf(wh - mn);
    const float cst = -0.70710678118654752f;
    const float upper = 0.5f * erfcf(cst * (0.5f - vv) / sc);
    const float lower = 0.5f * erfcf(cst * (-0.5f - vv) / sc);
    lik[base] = fmaxf(upper - lower, 1e-9f);

    float acc = wh;
#pragma unroll 8
    for (int j = 0; j < 64; ++j) {
        const float yj = __shfl(acc, j, 64);
        const float hv = (j < lane) ? hrow[j] : 0.f;
        acc = fmaf(hv, yj, acc);
    }
    y[base] = acc;
}

// ---------------------------------------------------------------------------
extern "C" void kernel_launch(void* const* d_in, const int* in_sizes, int n_in,
                              void* d_out, int out_size, void* d_ws, size_t ws_size,
                              hipStream_t stream)
{
    (void)in_sizes; (void)n_in; (void)out_size; (void)ws_size;

    const float* x      = (const float*)d_in[0];
    const float* noise  = (const float*)d_in[1];
    const float* w1     = (const float*)d_in[2];
    const float* b1     = (const float*)d_in[3];
    const float* beta1  = (const float*)d_in[4];
    const float* gamma1 = (const float*)d_in[5];
    const float* w2     = (const float*)d_in[6];
    const float* b2     = (const float*)d_in[7];
    const float* beta2  = (const float*)d_in[8];
    const float* gamma2 = (const float*)d_in[9];
    const float* w3     = (const float*)d_in[10];
    const float* b3     = (const float*)d_in[11];
    const float* dw1    = (const float*)d_in[12];
    const float* db1    = (const float*)d_in[13];
    const float* ibeta1 = (const float*)d_in[14];
    const float* igamma1= (const float*)d_in[15];
    const float* dw2    = (const float*)d_in[16];
    const float* db2    = (const float*)d_in[17];
    const float* ibeta2 = (const float*)d_in[18];
    const float* igamma2= (const float*)d_in[19];
    const float* dw3    = (const float*)d_in[20];
    const float* db3    = (const float*)d_in[21];
    const float* mean   = (const float*)d_in[22];
    const float* scale  = (const float*)d_in[23];
    const float* H      = (const float*)d_in[24];

    float* outp = (float*)d_out;
    float* xhat = outp;                                   // [1024,2,32,32]
    float* lik  = outp + (size_t)1024 * 2 * 32 * 32;      // [1024,320,64]

    // workspace layout (335.5 MB peak, regions reused once dead):
    //   off 0        : a1 [B,256,256] (268 MB) -> later y/y_hat [B,320,64] -> later d2 [B,256,256]
    //   off 268 MB   : a2 [B,256,64]  (67 MB)  -> later d1 [B,256,64]
    char* ws = (char*)d_ws;
    float* a1 = (float*)(ws);
    float* a2 = (float*)(ws + (size_t)268435456);
    float* y  = (float*)(ws);            // overlaps a1 (a1 dead after conv2)
    float* d1 = (float*)(ws + (size_t)268435456); // overlaps a2 (dead after conv3)
    float* d2 = (float*)(ws);            // overlaps y (dead after deconv1)

    // ---- analysis ----
    conv5k<2, 256, 32, 32, 2, 2, 16><<<dim3(1024, 16), 256, 0, stream>>>(x, w1, b1, a1);
    gdnk<256, false><<<dim3(1024, 4), 256, 0, stream>>>(a1, beta1, gamma1);
    conv5k<256, 256, 16, 16, 2, 32, 32><<<dim3(1024, 8), 256, 0, stream>>>(a1, w2, b2, a2);
    gdnk<64, false><<<dim3(1024, 1), 256, 0, stream>>>(a2, beta2, gamma2);
    conv5k<256, 320, 8, 8, 1, 64, 40><<<dim3(1024, 8), 256, 0, stream>>>(a2, w3, b3, y);

    // ---- context model: w_res, noise, likelihoods, triangular solve ----
    trik<<<dim3(320, 256), 256, 0, stream>>>(y, noise, H, mean, scale, lik);

    // ---- synthesis ----
    deconv1k<320, 256, 8, 64, 32><<<dim3(1024, 8), 256, 0, stream>>>(y, dw1, db1, d1);
    gdnk<64, true><<<dim3(1024, 1), 256, 0, stream>>>(d1, ibeta1, igamma1);
    deconv2k<256, 256, 8, 8, 64, 32, false><<<dim3(1024, 8), 256, 0, stream>>>(d1, dw2, db2, d2);
    gdnk<256, true><<<dim3(1024, 4), 256, 0, stream>>>(d2, ibeta2, igamma2);
    deconv2k<256, 2, 16, 16, 32, 2, true><<<dim3(1024, 1), 256, 0, stream>>>(d2, dw3, db3, xhat);
}

// Round 2
// 9559.052 us; speedup vs baseline: 6.3411x; 6.3411x over previous
//
#include <hip/hip_runtime.h>
#include <math.h>

typedef unsigned short u16;
typedef __bf16 bf16x8 __attribute__((ext_vector_type(8)));
typedef float f32x4 __attribute__((ext_vector_type(4)));
struct alignas(8) u16x4 { u16 a, b, c, d; };

__device__ __forceinline__ int ufl(int v) { return __builtin_amdgcn_readfirstlane(v); }
__device__ __forceinline__ u16 f2b(float f) {
    unsigned u = __float_as_uint(f);
    return (u16)((u + 0x7FFFu + ((u >> 16) & 1u)) >> 16);   // RNE fp32->bf16
}
__device__ __forceinline__ float b2f(u16 h) { return __uint_as_float(((unsigned)h) << 16); }
__device__ __forceinline__ float ldv(const float* p) { return *p; }
__device__ __forceinline__ float ldv(const u16* p)   { return b2f(*p); }
__device__ __forceinline__ void  stv(float* p, float v) { *p = v; }
__device__ __forceinline__ void  stv(u16* p, float v)   { *p = f2b(v); }
__device__ __forceinline__ u16 tob(float v) { return f2b(v); }
__device__ __forceinline__ u16 tob(u16 v)   { return v; }

// ---------------------------------------------------------------------------
// Weight repacks (run every call; d_ws is re-poisoned). All tiny.
// ---------------------------------------------------------------------------
// forward conv: W[COUT][CIN][25] f32 -> A[25][COUT][CIN] bf16
template<int CIN, int COUT>
__global__ __launch_bounds__(256) void rk_fwd(const float* __restrict__ w, u16* __restrict__ a) {
    int i = blockIdx.x * 256 + threadIdx.x;
    if (i >= 25 * COUT * CIN) return;
    int ci = i % CIN; int r = i / CIN; int co = r % COUT; int t = r / COUT;
    a[i] = f2b(w[(co * CIN + ci) * 25 + t]);
}
// deconv1 (s1 gather): W[320ci][256co][25] -> A[t'][256co][320ci], t'=(4-ky)*5+(4-kx)
__global__ __launch_bounds__(256) void rk_d1(const float* __restrict__ w, u16* __restrict__ a) {
    int i = blockIdx.x * 256 + threadIdx.x;
    if (i >= 25 * 256 * 320) return;
    int ci = i % 320; int r = i / 320; int co = r % 256; int tp = r / 256;
    int ky = 4 - tp / 5, kx = 4 - tp % 5;
    a[i] = f2b(w[(ci * 256 + co) * 25 + ky * 5 + kx]);
}
// deconv2 (s2 parity): W[256ci][256co][25] -> A2[q*9+tt][256co][256ci], zero for invalid taps
__global__ __launch_bounds__(256) void rk_d2(const float* __restrict__ w, u16* __restrict__ a) {
    int i = blockIdx.x * 256 + threadIdx.x;
    if (i >= 36 * 256 * 256) return;
    int ci = i % 256; int r = i / 256; int co = r % 256; int qt = r / 256;
    int q = qt / 9, tt = qt % 9;
    int qy = q >> 1, qx = q & 1, ty = tt / 3, tx = tt % 3;
    float v = 0.f;
    if (ty < 3 - qy && tx < 3 - qx) v = w[(ci * 256 + co) * 25 + (qy + 2 * ty) * 5 + (qx + 2 * tx)];
    a[i] = f2b(v);
}
// deconv3: W[256ci][2co][25] f32 -> W3r[4q][256ci][2co][16] f32 (9 taps zero-padded)
__global__ __launch_bounds__(256) void rk_d3(const float* __restrict__ w, float* __restrict__ a) {
    int i = blockIdx.x * 256 + threadIdx.x;
    if (i >= 4 * 256 * 2 * 16) return;
    int t = i % 16; int r = i / 16; int co = r % 2; int r2 = r / 2; int ci = r2 % 256; int q = r2 / 256;
    int qy = q >> 1, qx = q & 1;
    float v = 0.f;
    if (t < 9) {
        int ty = t / 3, tx = t % 3;
        if (ty < 3 - qy && tx < 3 - qx) v = w[(ci * 2 + co) * 25 + (qy + 2 * ty) * 5 + (qx + 2 * tx)];
    }
    a[i] = v;
}

// ---------------------------------------------------------------------------
// MFMA implicit-GEMM conv (k=5 pad=2 stride S in {1,2}), out always 8x8 per image.
// Block = 4 waves; wave w covers co [w*MT*16, ..). A repacked [25][COUT][CIN] bf16.
// LDS: input staged [spatial HPxHP][ci chunk] bf16, zero halo, stride CHUNK+8.
// Fragment layouts (m89/m120-verified): A: m=lane&15, k=quad*8+j; B: n=lane&15,
// k=quad*8+j; D: row=quad*4+reg, col=lane&15.
// ---------------------------------------------------------------------------
template<int CIN, int COUT, int S, int MT, typename TIN>
__global__ __launch_bounds__(256)
void mconv(const TIN* __restrict__ in, const u16* __restrict__ A,
           const float* __restrict__ bias, float* __restrict__ out)
{
    constexpr int HIN = 8 * S, HP = 7 * S + 5, CHUNK = 64, STRIDE = CHUNK + 8;
    constexpr int NCH = CIN / CHUNK;
    constexpr int SP = HP * HP;
    __shared__ u16 bs[SP * STRIDE];

    const int b = blockIdx.x;
    const int tid = threadIdx.x;
    const int lane = tid & 63, wv = tid >> 6;
    const int lm = lane & 15, quad = lane >> 4;
    const int cob = wv * (MT * 16);
    const TIN* inb = in + (size_t)b * CIN * (HIN * HIN);

    int bofs[4];
#pragma unroll
    for (int nt = 0; nt < 4; ++nt) {
        int px = nt * 16 + lm, oy = px >> 3, ox = px & 7;
        bofs[nt] = (S * oy * HP + S * ox) * STRIDE + quad * 8;
    }

    f32x4 acc[MT][4];
#pragma unroll
    for (int m = 0; m < MT; ++m)
#pragma unroll
        for (int n = 0; n < 4; ++n) acc[m][n] = (f32x4){0.f, 0.f, 0.f, 0.f};

#pragma unroll 1
    for (int ch = 0; ch < NCH; ++ch) {
        if (ch) __syncthreads();
        unsigned* bz = (unsigned*)bs;
        for (int i = tid; i < SP * STRIDE / 2; i += 256) bz[i] = 0u;
        __syncthreads();
        for (int i = tid; i < (CHUNK / 4) * (HIN * HIN); i += 256) {
            int px = i % (HIN * HIN), cg = i / (HIN * HIN);
            int iy = px / HIN, ix = px % HIN;
            const TIN* ip = inb + (size_t)(ch * CHUNK + cg * 4) * (HIN * HIN) + px;
            u16x4 p;
            p.a = tob(ip[0]);
            p.b = tob(ip[HIN * HIN]);
            p.c = tob(ip[2 * HIN * HIN]);
            p.d = tob(ip[3 * HIN * HIN]);
            *(u16x4*)&bs[((iy + 2) * HP + ix + 2) * STRIDE + cg * 4] = p;
        }
        __syncthreads();

#pragma unroll 1
        for (int tap = 0; tap < 25; ++tap) {
            const int ky = tap / 5, kx = tap % 5;
            const int tofs = (ky * HP + kx) * STRIDE;
            const u16* At = A + (size_t)tap * COUT * CIN + ch * CHUNK + quad * 8;
#pragma unroll
            for (int kc = 0; kc < CHUNK / 32; ++kc) {
                bf16x8 bf[4];
#pragma unroll
                for (int nt = 0; nt < 4; ++nt)
                    bf[nt] = *(const bf16x8*)&bs[bofs[nt] + tofs + kc * 32];
                bf16x8 af[MT];
#pragma unroll
                for (int m = 0; m < MT; ++m)
                    af[m] = *(const bf16x8*)(At + (size_t)(cob + m * 16 + lm) * CIN + kc * 32);
#pragma unroll
                for (int m = 0; m < MT; ++m)
#pragma unroll
                    for (int nt = 0; nt < 4; ++nt)
                        acc[m][nt] = __builtin_amdgcn_mfma_f32_16x16x32_bf16(af[m], bf[nt], acc[m][nt], 0, 0, 0);
            }
        }
    }

    float* ob = out + (size_t)b * COUT * 64;
#pragma unroll
    for (int m = 0; m < MT; ++m)
#pragma unroll
        for (int nt = 0; nt < 4; ++nt) {
            int px = nt * 16 + lm;
#pragma unroll
            for (int r = 0; r < 4; ++r) {
                int co = cob + m * 16 + quad * 4 + r;
                ob[(size_t)co * 64 + px] = acc[m][nt][r] + bias[co];
            }
        }
}

// ---------------------------------------------------------------------------
// MFMA ConvTranspose2d k=5 s=2 p=2 op=1, 8x8 -> 16x16, 256->256, out bf16.
// Parity decomposition: out[2s+q] = sum_t w[q+2t] * inpad[s+2-t] (halo 1).
// A2 repacked [q*9+tt][co][ci] bf16. Full 256-ci LDS stage (10x10 spatial).
// ---------------------------------------------------------------------------
__global__ __launch_bounds__(256)
void mdeconv2(const float* __restrict__ in, const u16* __restrict__ A2,
              const float* __restrict__ bias, u16* __restrict__ out)
{
    constexpr int STRIDE = 264;
    __shared__ u16 bs[100 * STRIDE];
    const int b = blockIdx.x, tid = threadIdx.x;
    const int lane = tid & 63, wv = tid >> 6, lm = lane & 15, quad = lane >> 4;
    const int cob = wv * 64;
    const float* inb = in + (size_t)b * 256 * 64;

    unsigned* bz = (unsigned*)bs;
    for (int i = tid; i < 100 * STRIDE / 2; i += 256) bz[i] = 0u;
    __syncthreads();
    for (int i = tid; i < 64 * 64; i += 256) {
        int px = i & 63, cg = i >> 6;
        int iy = px >> 3, ix = px & 7;
        const float* ip = inb + (size_t)cg * 4 * 64 + px;
        u16x4 p;
        p.a = f2b(ip[0]); p.b = f2b(ip[64]); p.c = f2b(ip[128]); p.d = f2b(ip[192]);
        *(u16x4*)&bs[((iy + 1) * 10 + ix + 1) * STRIDE + cg * 4] = p;
    }
    __syncthreads();

    int bofs[4];
#pragma unroll
    for (int nt = 0; nt < 4; ++nt) {
        int sp = nt * 16 + lm, sy = sp >> 3, sx = sp & 7;
        bofs[nt] = ((sy + 2) * 10 + sx + 2) * STRIDE + quad * 8;
    }

    u16* ob = out + (size_t)b * 256 * 256;
#pragma unroll
    for (int qy = 0; qy < 2; ++qy)
#pragma unroll
        for (int qx = 0; qx < 2; ++qx) {
            const int q = qy * 2 + qx;
            f32x4 acc[4][4];
#pragma unroll
            for (int m = 0; m < 4; ++m)
#pragma unroll
                for (int n = 0; n < 4; ++n) acc[m][n] = (f32x4){0.f, 0.f, 0.f, 0.f};

            const int NT = (3 - qy) * (3 - qx);
#pragma unroll 1
            for (int tt = 0; tt < NT; ++tt) {
                const int ty = tt / (3 - qx), tx = tt % (3 - qx);
                const int tofs = -(ty * 10 + tx) * STRIDE;
                const u16* At = A2 + (size_t)(q * 9 + ty * 3 + tx) * 256 * 256 + quad * 8;
#pragma unroll
                for (int kc = 0; kc < 8; ++kc) {
                    bf16x8 bf[4];
#pragma unroll
                    for (int nt = 0; nt < 4; ++nt)
                        bf[nt] = *(const bf16x8*)&bs[bofs[nt] + tofs + kc * 32];
                    bf16x8 af[4];
#pragma unroll
                    for (int m = 0; m < 4; ++m)
                        af[m] = *(const bf16x8*)(At + (size_t)(cob + m * 16 + lm) * 256 + kc * 32);
#pragma unroll
                    for (int m = 0; m < 4; ++m)
#pragma unroll
                        for (int nt = 0; nt < 4; ++nt)
                            acc[m][nt] = __builtin_amdgcn_mfma_f32_16x16x32_bf16(af[m], bf[nt], acc[m][nt], 0, 0, 0);
                }
            }
#pragma unroll
            for (int m = 0; m < 4; ++m)
#pragma unroll
                for (int nt = 0; nt < 4; ++nt) {
                    int sp = nt * 16 + lm, sy = sp >> 3, sx = sp & 7;
                    int opx = (2 * sy + qy) * 16 + 2 * sx + qx;
#pragma unroll
                    for (int r = 0; r < 4; ++r) {
                        int co = cob + m * 16 + quad * 4 + r;
                        ob[(size_t)co * 256 + opx] = f2b(acc[m][nt][r] + bias[co]);
                    }
                }
        }
}

// ---------------------------------------------------------------------------
// deconv3 (VALU): ConvTranspose2d s2, 256->2, 16x16 -> 32x32, clip [0,1].
// Input d2 bf16; weights repacked [q][ci][co][16] f32 -> contiguous wide s_loads,
// branch-free 9-tap FMA (invalid taps zero-padded at repack).
// ---------------------------------------------------------------------------
__global__ __launch_bounds__(256)
void dec3k(const u16* __restrict__ in, const float* __restrict__ W3r,
           const float* __restrict__ bias, float* __restrict__ out)
{
    constexpr int HT = 18;
    __shared__ float ls[32 * HT * HT];
    const int b = blockIdx.x, tid = threadIdx.x;
    const int sy = tid >> 4, sx = tid & 15;
    const u16* inb = in + (size_t)b * 256 * 256;
    float acc[4][2] = {};
#pragma unroll 1
    for (int ch = 0; ch < 8; ++ch) {
        if (ch) __syncthreads();
        for (int i = tid; i < 32 * HT * HT; i += 256) ls[i] = 0.f;
        __syncthreads();
        for (int i = tid; i < 32 * 256; i += 256) {
            int ci = i >> 8, px = i & 255, iy = px >> 4, ix = px & 15;
            ls[ci * (HT * HT) + (iy + 1) * HT + ix + 1] = b2f(inb[(size_t)(ch * 32 + ci) * 256 + px]);
        }
        __syncthreads();
#pragma unroll 1
        for (int ci = 0; ci < 32; ++ci) {
            float v[9];
            const float* l = &ls[ci * (HT * HT) + (sy + 2) * HT + sx + 2];
#pragma unroll
            for (int ty = 0; ty < 3; ++ty)
#pragma unroll
                for (int tx = 0; tx < 3; ++tx) v[ty * 3 + tx] = l[-(ty * HT) - tx];
#pragma unroll
            for (int q = 0; q < 4; ++q) {
                const float* wp = W3r + (size_t)ufl(((q * 256 + ch * 32 + ci) * 2) * 16);
#pragma unroll
                for (int t = 0; t < 9; ++t) {
                    acc[q][0] = fmaf(wp[t], v[t], acc[q][0]);
                    acc[q][1] = fmaf(wp[16 + t], v[t], acc[q][1]);
                }
            }
        }
    }
    float* ob = out + (size_t)b * 2 * 1024;
#pragma unroll
    for (int q = 0; q < 4; ++q) {
        int qy = q >> 1, qx = q & 1;
        int oy = 2 * sy + qy, ox = 2 * sx + qx;
#pragma unroll
        for (int co = 0; co < 2; ++co) {
            float r = acc[q][co] + bias[co];
            r = fminf(fmaxf(r, 0.f), 1.f);
            ob[(size_t)co * 1024 + oy * 32 + ox] = r;
        }
    }
}

// ---------------------------------------------------------------------------
// conv1: direct conv (CIN=2), unchanged from round 1 except bf16 output.
// ---------------------------------------------------------------------------
template<int CIN, int COUT, int HIN, int WIN, int S, int CI_CHUNK, int CO_PER_BLOCK, typename TOUT>
__global__ __launch_bounds__(256)
void conv5k(const float* __restrict__ in, const float* __restrict__ wt,
            const float* __restrict__ bias, TOUT* __restrict__ out)
{
    constexpr int HOUT = HIN / S, WOUT = WIN / S;
    constexpr int PX = HOUT * WOUT;
    constexpr int NCOG = (PX >= 256) ? 1 : (256 / PX);
    constexpr int CO_ITERS = CO_PER_BLOCK / NCOG;
    constexpr int HT = HIN + 4, WT = WIN + 4;
    constexpr int NCHUNK = CIN / CI_CHUNK;
    constexpr int TILE = CI_CHUNK * HT * WT;

    __shared__ float lds[TILE];

    const int b = blockIdx.x;
    const int co_base = blockIdx.y * CO_PER_BLOCK;
    const int tid = threadIdx.x;
    const int px = (PX >= 256) ? tid : (tid & (PX - 1));
    const int cog = (PX >= 256) ? 0 : (tid / PX);
    const int oy = px / WOUT, ox = px % WOUT;

    float acc[CO_ITERS];
#pragma unroll
    for (int i = 0; i < CO_ITERS; ++i) acc[i] = 0.f;

    const float* inb = in + (size_t)b * CIN * HIN * WIN;

#pragma unroll 1
    for (int ch = 0; ch < NCHUNK; ++ch) {
        if (ch) __syncthreads();
        for (int idx = tid; idx < TILE; idx += 256) lds[idx] = 0.f;
        __syncthreads();
        for (int idx = tid; idx < CI_CHUNK * HIN * WIN; idx += 256) {
            int ci = idx / (HIN * WIN);
            int r = idx - ci * (HIN * WIN);
            int iy = r / WIN, ix = r - iy * WIN;
            lds[ci * (HT * WT) + (iy + 2) * WT + (ix + 2)] =
                inb[(size_t)(ch * CI_CHUNK + ci) * (HIN * WIN) + r];
        }
        __syncthreads();

#pragma unroll 1
        for (int ci = 0; ci < CI_CHUNK; ++ci) {
            float v[25];
            const float* l = &lds[ci * (HT * WT) + (oy * S) * WT + (ox * S)];
#pragma unroll
            for (int ky = 0; ky < 5; ++ky)
#pragma unroll
                for (int kx = 0; kx < 5; ++kx)
                    v[ky * 5 + kx] = l[ky * WT + kx];
#pragma unroll
            for (int i = 0; i < CO_ITERS; ++i) {
                const int co = co_base + cog * CO_ITERS + i;
                const float* wp = wt + (size_t)ufl((co * CIN + ch * CI_CHUNK + ci) * 25);
#pragma unroll
                for (int t = 0; t < 25; ++t) acc[i] = fmaf(wp[t], v[t], acc[i]);
            }
        }
    }

#pragma unroll
    for (int i = 0; i < CO_ITERS; ++i) {
        const int co = co_base + cog * CO_ITERS + i;
        stv(&out[((size_t)b * COUT + co) * PX + px], acc[i] + bias[co]);
    }
}

// ---------------------------------------------------------------------------
// GDN (in-place), templated on tensor storage type (f32 or bf16).
// ---------------------------------------------------------------------------
template<typename T, int P_IMG, bool INVERSE>
__global__ __launch_bounds__(256)
void gdnk(T* __restrict__ x, const float* __restrict__ beta,
          const float* __restrict__ gamma)
{
    __shared__ float xs[256 * 64];
    const int b = blockIdx.x;
    const int pb = blockIdx.y * 64;
    const int tid = threadIdx.x;
    const int px = tid & 63;
    const int og = tid >> 6;

    T* xb = x + (size_t)b * 256 * P_IMG + pb;

#pragma unroll 4
    for (int k = 0; k < 64; ++k) {
        const int c = og + 4 * k;
        xs[c * 64 + px] = ldv(&xb[(size_t)c * P_IMG + px]);
    }
    __syncthreads();

    const int co0 = og * 64;
    float acc[64];
#pragma unroll
    for (int k = 0; k < 64; ++k) acc[k] = beta[ufl(co0 + k)];

#pragma unroll 1
    for (int cc = 0; cc < 32; ++cc) {
        float xv[8];
#pragma unroll
        for (int u = 0; u < 8; ++u) {
            float t = xs[(cc * 8 + u) * 64 + px];
            xv[u] = t * t;
        }
#pragma unroll
        for (int k = 0; k < 64; ++k) {
            const float* g = gamma + (size_t)ufl((co0 + k) * 256 + cc * 8);
#pragma unroll
            for (int u = 0; u < 8; ++u) acc[k] = fmaf(g[u], xv[u], acc[k]);
        }
    }

#pragma unroll 4
    for (int k = 0; k < 64; ++k) {
        const float n = acc[k];
        const float r = INVERSE ? sqrtf(n) : rsqrtf(n);
        stv(&xb[(size_t)(co0 + k) * P_IMG + px], xs[(co0 + k) * 64 + px] * r);
    }
}

// ---------------------------------------------------------------------------
// Fused context model (unchanged from round 1, verified).
// ---------------------------------------------------------------------------
__global__ __launch_bounds__(256)
void trik(float* __restrict__ y, const float* __restrict__ noise,
          const float* __restrict__ H, const float* __restrict__ mean,
          const float* __restrict__ scale, float* __restrict__ lik)
{
    __shared__ float h[64 * 65];
    const int c = blockIdx.x;
    const int bt = blockIdx.y;
    const int tid = threadIdx.x;
    const int lane = tid & 63;
    const int wv = tid >> 6;

    const float* Hc = H + (size_t)c * 4096;
    for (int idx = tid; idx < 4096; idx += 256) {
        const int i = idx >> 6, j = idx & 63;
        h[i * 65 + j] = Hc[idx];
    }
    __syncthreads();

    const int b = bt * 4 + wv;
    const size_t base = ((size_t)b * 320 + c) * 64 + lane;
    const float* hrow = &h[lane * 65];

    const float yv = y[base];
    float ws = 0.f;
#pragma unroll 8
    for (int j = 0; j < 64; ++j) {
        const float yj = __shfl(yv, j, 64);
        const float hv = (j < lane) ? hrow[j] : 0.f;
        ws = fmaf(hv, yj, ws);
    }
    const float wh = yv - ws + noise[base];

    const float mn = mean[c * 64 + lane];
    const float sc = fmaxf(scale[c * 64 + lane], 0.11f);
    const float vv = fabsf(wh - mn);
    const float cst = -0.70710678118654752f;
    const float upper = 0.5f * erfcf(cst * (0.5f - vv) / sc);
    const float lower = 0.5f * erfcf(cst * (-0.5f - vv) / sc);
    lik[base] = fmaxf(upper - lower, 1e-9f);

    float acc = wh;
#pragma unroll 8
    for (int j = 0; j < 64; ++j) {
        const float yj = __shfl(acc, j, 64);
        const float hv = (j < lane) ? hrow[j] : 0.f;
        acc = fmaf(hv, yj, acc);
    }
    y[base] = acc;
}

// ---------------------------------------------------------------------------
extern "C" void kernel_launch(void* const* d_in, const int* in_sizes, int n_in,
                              void* d_out, int out_size, void* d_ws, size_t ws_size,
                              hipStream_t stream)
{
    (void)in_sizes; (void)n_in; (void)out_size; (void)ws_size;

    const float* x      = (const float*)d_in[0];
    const float* noise  = (const float*)d_in[1];
    const float* w1     = (const float*)d_in[2];
    const float* b1     = (const float*)d_in[3];
    const float* beta1  = (const float*)d_in[4];
    const float* gamma1 = (const float*)d_in[5];
    const float* w2     = (const float*)d_in[6];
    const float* b2     = (const float*)d_in[7];
    const float* beta2  = (const float*)d_in[8];
    const float* gamma2 = (const float*)d_in[9];
    const float* w3     = (const float*)d_in[10];
    const float* b3     = (const float*)d_in[11];
    const float* dw1    = (const float*)d_in[12];
    const float* db1    = (const float*)d_in[13];
    const float* ibeta1 = (const float*)d_in[14];
    const float* igamma1= (const float*)d_in[15];
    const float* dw2    = (const float*)d_in[16];
    const float* db2    = (const float*)d_in[17];
    const float* ibeta2 = (const float*)d_in[18];
    const float* igamma2= (const float*)d_in[19];
    const float* dw3    = (const float*)d_in[20];
    const float* db3    = (const float*)d_in[21];
    const float* mean   = (const float*)d_in[22];
    const float* scale  = (const float*)d_in[23];
    const float* H      = (const float*)d_in[24];

    float* outp = (float*)d_out;
    float* xhat = outp;                                   // [1024,2,32,32]
    float* lik  = outp + (size_t)1024 * 2 * 32 * 32;      // [1024,320,64]

    // workspace layout (peak 217.6 MB < round-1-proven 335.5 MB):
    //   [0, 134.2M)      a1 bf16 -> y f32 -> d2 bf16
    //   [134.2M, 201.3M) a2 f32 -> d1 f32
    //   [201.3M, 217.6M) repacked weights (live whole call)
    char* ws = (char*)d_ws;
    u16*   a1  = (u16*)ws;
    float* a2  = (float*)(ws + 134217728);
    float* y   = (float*)ws;
    float* d1  = (float*)(ws + 134217728);
    u16*   d2  = (u16*)ws;
    u16*   Ac2 = (u16*)(ws + 201326592);
    u16*   Ac3 = (u16*)(ws + 204603392);
    u16*   Ad1 = (u16*)(ws + 208699392);
    u16*   Ad2 = (u16*)(ws + 212795392);
    float* W3r = (float*)(ws + 217513984);

    // ---- weight repacks ----
    rk_fwd<256, 256><<<6400, 256, 0, stream>>>(w2, Ac2);
    rk_fwd<256, 320><<<8000, 256, 0, stream>>>(w3, Ac3);
    rk_d1<<<8000, 256, 0, stream>>>(dw1, Ad1);
    rk_d2<<<9216, 256, 0, stream>>>(dw2, Ad2);
    rk_d3<<<128, 256, 0, stream>>>(dw3, W3r);

    // ---- analysis ----
    conv5k<2, 256, 32, 32, 2, 2, 16, u16><<<dim3(1024, 16), 256, 0, stream>>>(x, w1, b1, a1);
    gdnk<u16, 256, false><<<dim3(1024, 4), 256, 0, stream>>>(a1, beta1, gamma1);
    mconv<256, 256, 2, 4, u16><<<1024, 256, 0, stream>>>(a1, Ac2, b2, a2);
    gdnk<float, 64, false><<<dim3(1024, 1), 256, 0, stream>>>(a2, beta2, gamma2);
    mconv<256, 320, 1, 5, float><<<1024, 256, 0, stream>>>(a2, Ac3, b3, y);

    // ---- context model ----
    trik<<<dim3(320, 256), 256, 0, stream>>>(y, noise, H, mean, scale, lik);

    // ---- synthesis ----
    mconv<320, 256, 1, 4, float><<<1024, 256, 0, stream>>>(y, Ad1, db1, d1);
    gdnk<float, 64, true><<<dim3(1024, 1), 256, 0, stream>>>(d1, ibeta1, igamma1);
    mdeconv2<<<1024, 256, 0, stream>>>(d1, Ad2, db2, d2);
    gdnk<u16, 256, true><<<dim3(1024, 4), 256, 0, stream>>>(d2, ibeta2, igamma2);
    dec3k<<<1024, 256, 0, stream>>>(d2, W3r, db3, xhat);
}

// Round 3
// 9413.177 us; speedup vs baseline: 6.4394x; 1.0155x over previous
//
#include <hip/hip_runtime.h>
#include <math.h>

typedef unsigned short u16;
typedef __bf16 bf16x8 __attribute__((ext_vector_type(8)));
typedef float f32x4 __attribute__((ext_vector_type(4)));
struct alignas(8) u16x4 { u16 x0, x1, x2, x3; };

__device__ __forceinline__ int ufl(int v) { return __builtin_amdgcn_readfirstlane(v); }
__device__ __forceinline__ u16 f2b(float f) {
    unsigned u = __float_as_uint(f);
    return (u16)((u + 0x7FFFu + ((u >> 16) & 1u)) >> 16);   // RNE fp32->bf16
}
__device__ __forceinline__ float b2f(u16 h) { return __uint_as_float(((unsigned)h) << 16); }
__device__ __forceinline__ float ldv(const float* p) { return *p; }
__device__ __forceinline__ float ldv(const u16* p)   { return b2f(*p); }
__device__ __forceinline__ u16 tob(float v) { return f2b(v); }
__device__ __forceinline__ u16 tob(u16 v)   { return v; }

// ---------------------------------------------------------------------------
// Weight repacks. NOTE: paired u32 stores — sub-dword global stores cost a
// full 128B HBM write block each on gfx950 (round-2 evidence: 65x write amp).
// ---------------------------------------------------------------------------
// forward conv: W[COUT][CIN][25] f32 -> A[25][COUT][CIN] bf16 (ci pairs)
template<int CIN, int COUT>
__global__ __launch_bounds__(256) void rk_fwd(const float* __restrict__ w, u16* __restrict__ a) {
    int j = (blockIdx.x * 256 + threadIdx.x) * 2;
    if (j >= 25 * COUT * CIN) return;
    int ci = j % CIN; int r = j / CIN; int co = r % COUT; int t = r / COUT;
    u16 lo = f2b(w[(co * CIN + ci) * 25 + t]);
    u16 hi = f2b(w[(co * CIN + ci + 1) * 25 + t]);
    *(unsigned*)&a[j] = (unsigned)lo | ((unsigned)hi << 16);
}
// deconv1 (s1 gather): W[320ci][256co][25] -> A[t'][256co][320ci], t'=(4-ky)*5+(4-kx)
__global__ __launch_bounds__(256) void rk_d1(const float* __restrict__ w, u16* __restrict__ a) {
    int j = (blockIdx.x * 256 + threadIdx.x) * 2;
    if (j >= 25 * 256 * 320) return;
    int ci = j % 320; int r = j / 320; int co = r % 256; int tp = r / 256;
    int ky = 4 - tp / 5, kx = 4 - tp % 5;
    u16 lo = f2b(w[(ci * 256 + co) * 25 + ky * 5 + kx]);
    u16 hi = f2b(w[((ci + 1) * 256 + co) * 25 + ky * 5 + kx]);
    *(unsigned*)&a[j] = (unsigned)lo | ((unsigned)hi << 16);
}
// deconv2 (s2 parity): W[256ci][256co][25] -> A2[q*9+tt][256co][256ci], zero invalid taps
__global__ __launch_bounds__(256) void rk_d2(const float* __restrict__ w, u16* __restrict__ a) {
    int j = (blockIdx.x * 256 + threadIdx.x) * 2;
    if (j >= 36 * 256 * 256) return;
    int ci = j % 256; int r = j / 256; int co = r % 256; int qt = r / 256;
    int q = qt / 9, tt = qt % 9;
    int qy = q >> 1, qx = q & 1, ty = tt / 3, tx = tt % 3;
    u16 lo = 0, hi = 0;
    if (ty < 3 - qy && tx < 3 - qx) {
        int widx = (qy + 2 * ty) * 5 + (qx + 2 * tx);
        lo = f2b(w[(ci * 256 + co) * 25 + widx]);
        hi = f2b(w[((ci + 1) * 256 + co) * 25 + widx]);
    }
    *(unsigned*)&a[j] = (unsigned)lo | ((unsigned)hi << 16);
}
// deconv3: W[256ci][2co][25] f32 -> W3r[4q][256ci][2co][16] f32 (9 taps zero-padded)
__global__ __launch_bounds__(256) void rk_d3(const float* __restrict__ w, float* __restrict__ a) {
    int i = blockIdx.x * 256 + threadIdx.x;
    if (i >= 4 * 256 * 2 * 16) return;
    int t = i % 16; int r = i / 16; int co = r % 2; int r2 = r / 2; int ci = r2 % 256; int q = r2 / 256;
    int qy = q >> 1, qx = q & 1;
    float v = 0.f;
    if (t < 9) {
        int ty = t / 3, tx = t % 3;
        if (ty < 3 - qy && tx < 3 - qx) v = w[(ci * 2 + co) * 25 + (qy + 2 * ty) * 5 + (qx + 2 * tx)];
    }
    a[i] = v;
}

// ---------------------------------------------------------------------------
// MFMA implicit-GEMM conv (k=5 pad=2 stride S in {1,2}), out 8x8 per image.
// (unchanged from round 2 — f32 dword stores, no amplification)
// ---------------------------------------------------------------------------
template<int CIN, int COUT, int S, int MT, typename TIN>
__global__ __launch_bounds__(256)
void mconv(const TIN* __restrict__ in, const u16* __restrict__ A,
           const float* __restrict__ bias, float* __restrict__ out)
{
    constexpr int HIN = 8 * S, HP = 7 * S + 5, CHUNK = 64, STRIDE = CHUNK + 8;
    constexpr int NCH = CIN / CHUNK;
    constexpr int SP = HP * HP;
    __shared__ u16 bs[SP * STRIDE];

    const int b = blockIdx.x;
    const int tid = threadIdx.x;
    const int lane = tid & 63, wv = tid >> 6;
    const int lm = lane & 15, quad = lane >> 4;
    const int cob = wv * (MT * 16);
    const TIN* inb = in + (size_t)b * CIN * (HIN * HIN);

    int bofs[4];
#pragma unroll
    for (int nt = 0; nt < 4; ++nt) {
        int px = nt * 16 + lm, oy = px >> 3, ox = px & 7;
        bofs[nt] = (S * oy * HP + S * ox) * STRIDE + quad * 8;
    }

    f32x4 acc[MT][4];
#pragma unroll
    for (int m = 0; m < MT; ++m)
#pragma unroll
        for (int n = 0; n < 4; ++n) acc[m][n] = (f32x4){0.f, 0.f, 0.f, 0.f};

#pragma unroll 1
    for (int ch = 0; ch < NCH; ++ch) {
        if (ch) __syncthreads();
        unsigned* bz = (unsigned*)bs;
        for (int i = tid; i < SP * STRIDE / 2; i += 256) bz[i] = 0u;
        __syncthreads();
        for (int i = tid; i < (CHUNK / 4) * (HIN * HIN); i += 256) {
            int px = i % (HIN * HIN), cg = i / (HIN * HIN);
            int iy = px / HIN, ix = px % HIN;
            const TIN* ip = inb + (size_t)(ch * CHUNK + cg * 4) * (HIN * HIN) + px;
            u16x4 p;
            p.x0 = tob(ip[0]);
            p.x1 = tob(ip[HIN * HIN]);
            p.x2 = tob(ip[2 * HIN * HIN]);
            p.x3 = tob(ip[3 * HIN * HIN]);
            *(u16x4*)&bs[((iy + 2) * HP + ix + 2) * STRIDE + cg * 4] = p;
        }
        __syncthreads();

#pragma unroll 1
        for (int tap = 0; tap < 25; ++tap) {
            const int ky = tap / 5, kx = tap % 5;
            const int tofs = (ky * HP + kx) * STRIDE;
            const u16* At = A + (size_t)tap * COUT * CIN + ch * CHUNK + quad * 8;
#pragma unroll
            for (int kc = 0; kc < CHUNK / 32; ++kc) {
                bf16x8 bf[4];
#pragma unroll
                for (int nt = 0; nt < 4; ++nt)
                    bf[nt] = *(const bf16x8*)&bs[bofs[nt] + tofs + kc * 32];
                bf16x8 af[MT];
#pragma unroll
                for (int m = 0; m < MT; ++m)
                    af[m] = *(const bf16x8*)(At + (size_t)(cob + m * 16 + lm) * CIN + kc * 32);
#pragma unroll
                for (int m = 0; m < MT; ++m)
#pragma unroll
                    for (int nt = 0; nt < 4; ++nt)
                        acc[m][nt] = __builtin_amdgcn_mfma_f32_16x16x32_bf16(af[m], bf[nt], acc[m][nt], 0, 0, 0);
            }
        }
    }

    float* ob = out + (size_t)b * COUT * 64;
#pragma unroll
    for (int m = 0; m < MT; ++m)
#pragma unroll
        for (int nt = 0; nt < 4; ++nt) {
            int px = nt * 16 + lm;
#pragma unroll
            for (int r = 0; r < 4; ++r) {
                int co = cob + m * 16 + quad * 4 + r;
                ob[(size_t)co * 64 + px] = acc[m][nt][r] + bias[co];
            }
        }
}

// ---------------------------------------------------------------------------
// MFMA ConvTranspose2d k=5 s=2, 8x8 -> 16x16, 256->256, out bf16 QUADRANT-PLANAR:
// d2[b][q][co][sp] (sp = sy*8+sx). Each quadrant's output = one contiguous
// 32 KB chunk -> LDS bounce + u16x4 stores (no sub-dword global stores).
// ---------------------------------------------------------------------------
__global__ __launch_bounds__(256)
void mdeconv2(const float* __restrict__ in, const u16* __restrict__ A2,
              const float* __restrict__ bias, u16* __restrict__ out)
{
    constexpr int STRIDE = 264;
    __shared__ u16 bs[100 * STRIDE];
    __shared__ u16 os[256 * 64];
    const int b = blockIdx.x, tid = threadIdx.x;
    const int lane = tid & 63, wv = tid >> 6, lm = lane & 15, quad = lane >> 4;
    const int cob = wv * 64;
    const float* inb = in + (size_t)b * 256 * 64;

    unsigned* bz = (unsigned*)bs;
    for (int i = tid; i < 100 * STRIDE / 2; i += 256) bz[i] = 0u;
    __syncthreads();
    for (int i = tid; i < 64 * 64; i += 256) {
        int px = i & 63, cg = i >> 6;
        int iy = px >> 3, ix = px & 7;
        const float* ip = inb + (size_t)cg * 4 * 64 + px;
        u16x4 p;
        p.x0 = f2b(ip[0]); p.x1 = f2b(ip[64]); p.x2 = f2b(ip[128]); p.x3 = f2b(ip[192]);
        *(u16x4*)&bs[((iy + 1) * 10 + ix + 1) * STRIDE + cg * 4] = p;
    }
    __syncthreads();

    int bofs[4];
#pragma unroll
    for (int nt = 0; nt < 4; ++nt) {
        int sp = nt * 16 + lm, sy = sp >> 3, sx = sp & 7;
        bofs[nt] = ((sy + 2) * 10 + sx + 2) * STRIDE + quad * 8;
    }

#pragma unroll
    for (int qy = 0; qy < 2; ++qy)
#pragma unroll
        for (int qx = 0; qx < 2; ++qx) {
            const int q = qy * 2 + qx;
            f32x4 acc[4][4];
#pragma unroll
            for (int m = 0; m < 4; ++m)
#pragma unroll
                for (int n = 0; n < 4; ++n) acc[m][n] = (f32x4){0.f, 0.f, 0.f, 0.f};

            const int NT = (3 - qy) * (3 - qx);
#pragma unroll 1
            for (int tt = 0; tt < NT; ++tt) {
                const int ty = tt / (3 - qx), tx = tt % (3 - qx);
                const int tofs = -(ty * 10 + tx) * STRIDE;
                const u16* At = A2 + (size_t)(q * 9 + ty * 3 + tx) * 256 * 256 + quad * 8;
#pragma unroll
                for (int kc = 0; kc < 8; ++kc) {
                    bf16x8 bf[4];
#pragma unroll
                    for (int nt = 0; nt < 4; ++nt)
                        bf[nt] = *(const bf16x8*)&bs[bofs[nt] + tofs + kc * 32];
                    bf16x8 af[4];
#pragma unroll
                    for (int m = 0; m < 4; ++m)
                        af[m] = *(const bf16x8*)(At + (size_t)(cob + m * 16 + lm) * 256 + kc * 32);
#pragma unroll
                    for (int m = 0; m < 4; ++m)
#pragma unroll
                        for (int nt = 0; nt < 4; ++nt)
                            acc[m][nt] = __builtin_amdgcn_mfma_f32_16x16x32_bf16(af[m], bf[nt], acc[m][nt], 0, 0, 0);
                }
            }
            // bounce fragments -> LDS -> contiguous u16x4 stores
#pragma unroll
            for (int m = 0; m < 4; ++m)
#pragma unroll
                for (int nt = 0; nt < 4; ++nt)
#pragma unroll
                    for (int r = 0; r < 4; ++r) {
                        int co = cob + m * 16 + quad * 4 + r;
                        os[co * 64 + nt * 16 + lm] = f2b(acc[m][nt][r] + bias[co]);
                    }
            __syncthreads();
            u16* od = out + ((size_t)(b * 4 + q)) * 256 * 64;
#pragma unroll
            for (int it = 0; it < 16; ++it) {
                int v = it * 256 + tid;
                u16x4 p;
                p.x0 = os[v * 4]; p.x1 = os[v * 4 + 1]; p.x2 = os[v * 4 + 2]; p.x3 = os[v * 4 + 3];
                *(u16x4*)&od[v * 4] = p;
            }
            __syncthreads();
        }
}

// ---------------------------------------------------------------------------
// deconv3 (VALU): ConvTranspose2d s2, 256->2, 16x16 -> 32x32, clip [0,1].
// Input d2 bf16 QUADRANT-PLANAR [b][q][ci][sp]. f32 dword output stores.
// ---------------------------------------------------------------------------
__global__ __launch_bounds__(256)
void dec3k(const u16* __restrict__ in, const float* __restrict__ W3r,
           const float* __restrict__ bias, float* __restrict__ out)
{
    constexpr int HT = 18;
    __shared__ float ls[32 * HT * HT];
    const int b = blockIdx.x, tid = threadIdx.x;
    const int sy = tid >> 4, sx = tid & 15;
    const u16* inb = in + (size_t)b * 4 * 256 * 64;
    float acc[4][2] = {};
#pragma unroll 1
    for (int ch = 0; ch < 8; ++ch) {
        if (ch) __syncthreads();
        for (int i = tid; i < 32 * HT * HT; i += 256) ls[i] = 0.f;
        __syncthreads();
        for (int i = tid; i < 32 * 256; i += 256) {
            int ci = i >> 8, px = i & 255, iy = px >> 4, ix = px & 15;
            int q = (iy & 1) * 2 + (ix & 1);
            int sp = (iy >> 1) * 8 + (ix >> 1);
            ls[ci * (HT * HT) + (iy + 1) * HT + ix + 1] =
                b2f(inb[((size_t)q * 256 + ch * 32 + ci) * 64 + sp]);
        }
        __syncthreads();
#pragma unroll 1
        for (int ci = 0; ci < 32; ++ci) {
            float v[9];
            const float* l = &ls[ci * (HT * HT) + (sy + 2) * HT + sx + 2];
#pragma unroll
            for (int ty = 0; ty < 3; ++ty)
#pragma unroll
                for (int tx = 0; tx < 3; ++tx) v[ty * 3 + tx] = l[-(ty * HT) - tx];
#pragma unroll
            for (int q = 0; q < 4; ++q) {
                const float* wp = W3r + (size_t)ufl(((q * 256 + ch * 32 + ci) * 2) * 16);
#pragma unroll
                for (int t = 0; t < 9; ++t) {
                    acc[q][0] = fmaf(wp[t], v[t], acc[q][0]);
                    acc[q][1] = fmaf(wp[16 + t], v[t], acc[q][1]);
                }
            }
        }
    }
    float* ob = out + (size_t)b * 2 * 1024;
#pragma unroll
    for (int q = 0; q < 4; ++q) {
        int qy = q >> 1, qx = q & 1;
        int oy = 2 * sy + qy, ox = 2 * sx + qx;
#pragma unroll
        for (int co = 0; co < 2; ++co) {
            float r = acc[q][co] + bias[co];
            r = fminf(fmaxf(r, 0.f), 1.f);
            ob[(size_t)co * 1024 + oy * 32 + ox] = r;
        }
    }
}

// ---------------------------------------------------------------------------
// conv1: direct conv (CIN=2). bf16 output bounced through LDS -> u16x4 stores.
// Only instantiated with PX==256, NCOG==1.
// ---------------------------------------------------------------------------
template<int CIN, int COUT, int HIN, int WIN, int S, int CI_CHUNK, int CO_PER_BLOCK>
__global__ __launch_bounds__(256)
void conv5k(const float* __restrict__ in, const float* __restrict__ wt,
            const float* __restrict__ bias, u16* __restrict__ out)
{
    constexpr int HOUT = HIN / S, WOUT = WIN / S;
    constexpr int PX = HOUT * WOUT;          // 256
    constexpr int CO_ITERS = CO_PER_BLOCK;   // 16
    constexpr int HT = HIN + 4, WT = WIN + 4;
    constexpr int NCHUNK = CIN / CI_CHUNK;
    constexpr int TILE = CI_CHUNK * HT * WT;

    __shared__ float lds[TILE];
    __shared__ u16 os[CO_PER_BLOCK * PX];

    const int b = blockIdx.x;
    const int co_base = blockIdx.y * CO_PER_BLOCK;
    const int tid = threadIdx.x;
    const int px = tid;
    const int oy = px / WOUT, ox = px % WOUT;

    float acc[CO_ITERS];
#pragma unroll
    for (int i = 0; i < CO_ITERS; ++i) acc[i] = 0.f;

    const float* inb = in + (size_t)b * CIN * HIN * WIN;

#pragma unroll 1
    for (int ch = 0; ch < NCHUNK; ++ch) {
        if (ch) __syncthreads();
        for (int idx = tid; idx < TILE; idx += 256) lds[idx] = 0.f;
        __syncthreads();
        for (int idx = tid; idx < CI_CHUNK * HIN * WIN; idx += 256) {
            int ci = idx / (HIN * WIN);
            int r = idx - ci * (HIN * WIN);
            int iy = r / WIN, ix = r - iy * WIN;
            lds[ci * (HT * WT) + (iy + 2) * WT + (ix + 2)] =
                inb[(size_t)(ch * CI_CHUNK + ci) * (HIN * WIN) + r];
        }
        __syncthreads();

#pragma unroll 1
        for (int ci = 0; ci < CI_CHUNK; ++ci) {
            float v[25];
            const float* l = &lds[ci * (HT * WT) + (oy * S) * WT + (ox * S)];
#pragma unroll
            for (int ky = 0; ky < 5; ++ky)
#pragma unroll
                for (int kx = 0; kx < 5; ++kx)
                    v[ky * 5 + kx] = l[ky * WT + kx];
#pragma unroll
            for (int i = 0; i < CO_ITERS; ++i) {
                const int co = co_base + i;
                const float* wp = wt + (size_t)ufl((co * CIN + ch * CI_CHUNK + ci) * 25);
#pragma unroll
                for (int t = 0; t < 25; ++t) acc[i] = fmaf(wp[t], v[t], acc[i]);
            }
        }
    }

#pragma unroll
    for (int i = 0; i < CO_ITERS; ++i)
        os[i * PX + px] = f2b(acc[i] + bias[co_base + i]);
    __syncthreads();
    u16* ob = out + ((size_t)b * COUT + co_base) * PX;
#pragma unroll
    for (int it = 0; it < CO_PER_BLOCK * PX / 1024; ++it) {
        int v = it * 256 + tid;
        u16x4 p;
        p.x0 = os[v * 4]; p.x1 = os[v * 4 + 1]; p.x2 = os[v * 4 + 2]; p.x3 = os[v * 4 + 3];
        *(u16x4*)&ob[v * 4] = p;
    }
}

// ---------------------------------------------------------------------------
// GDN f32 (in-place, dword stores — fine). Used for a2 / d1 (P_IMG=64).
// ---------------------------------------------------------------------------
template<typename T, int P_IMG, bool INVERSE>
__global__ __launch_bounds__(256)
void gdnk(T* __restrict__ x, const float* __restrict__ beta,
          const float* __restrict__ gamma)
{
    __shared__ float xs[256 * 64];
    const int b = blockIdx.x;
    const int pb = blockIdx.y * 64;
    const int tid = threadIdx.x;
    const int px = tid & 63;
    const int og = tid >> 6;

    T* xb = x + (size_t)b * 256 * P_IMG + pb;

#pragma unroll 4
    for (int k = 0; k < 64; ++k) {
        const int c = og + 4 * k;
        xs[c * 64 + px] = ldv(&xb[(size_t)c * P_IMG + px]);
    }
    __syncthreads();

    const int co0 = og * 64;
    float acc[64];
#pragma unroll
    for (int k = 0; k < 64; ++k) acc[k] = beta[ufl(co0 + k)];

#pragma unroll 1
    for (int cc = 0; cc < 32; ++cc) {
        float xv[8];
#pragma unroll
        for (int u = 0; u < 8; ++u) {
            float t = xs[(cc * 8 + u) * 64 + px];
            xv[u] = t * t;
        }
#pragma unroll
        for (int k = 0; k < 64; ++k) {
            const float* g = gamma + (size_t)ufl((co0 + k) * 256 + cc * 8);
#pragma unroll
            for (int u = 0; u < 8; ++u) acc[k] = fmaf(g[u], xv[u], acc[k]);
        }
    }

#pragma unroll 4
    for (int k = 0; k < 64; ++k) {
        const float n = acc[k];
        const float r = INVERSE ? sqrtf(n) : rsqrtf(n);
        xb[(size_t)(co0 + k) * P_IMG + px] = xs[(co0 + k) * 64 + px] * r;
    }
}

// ---------------------------------------------------------------------------
// GDN bf16 (in-place) with vectorized u16x4 global I/O through the LDS tile.
// PLANAR=false: x is [b][256][256], block = (b, 64-px slice), row stride 256.
// PLANAR=true : x is [b*4+q][256][64] (quadrant-planar d2), row stride 64.
// Grid (1024, 4) in both cases.
// ---------------------------------------------------------------------------
template<bool INVERSE, bool PLANAR>
__global__ __launch_bounds__(256)
void gdnk16(u16* __restrict__ x, const float* __restrict__ beta,
            const float* __restrict__ gamma)
{
    constexpr int RS = PLANAR ? 64 : 256;
    __shared__ float xs[256 * 64];
    const int tid = threadIdx.x;
    u16* xb = x + (size_t)blockIdx.x * 65536 + (size_t)blockIdx.y * (PLANAR ? 16384 : 64);

#pragma unroll
    for (int it = 0; it < 16; ++it) {
        int v = it * 256 + tid;
        int ch = v >> 4, pxg = (v & 15) * 4;
        u16x4 p = *(const u16x4*)&xb[(size_t)ch * RS + pxg];
        f32x4 f = {b2f(p.x0), b2f(p.x1), b2f(p.x2), b2f(p.x3)};
        *(f32x4*)&xs[ch * 64 + pxg] = f;
    }
    __syncthreads();

    const int px = tid & 63, og = tid >> 6, co0 = og * 64;
    float acc[64];
#pragma unroll
    for (int k = 0; k < 64; ++k) acc[k] = beta[ufl(co0 + k)];

#pragma unroll 1
    for (int cc = 0; cc < 32; ++cc) {
        float xv[8];
#pragma unroll
        for (int u = 0; u < 8; ++u) {
            float t = xs[(cc * 8 + u) * 64 + px];
            xv[u] = t * t;
        }
#pragma unroll
        for (int k = 0; k < 64; ++k) {
            const float* g = gamma + (size_t)ufl((co0 + k) * 256 + cc * 8);
#pragma unroll
            for (int u = 0; u < 8; ++u) acc[k] = fmaf(g[u], xv[u], acc[k]);
        }
    }

    // in-place multiply in LDS (each element owned by exactly one thread)
#pragma unroll 4
    for (int k = 0; k < 64; ++k) {
        const float n = acc[k];
        const float r = INVERSE ? sqrtf(n) : rsqrtf(n);
        xs[(co0 + k) * 64 + px] *= r;
    }
    __syncthreads();

#pragma unroll
    for (int it = 0; it < 16; ++it) {
        int v = it * 256 + tid;
        int ch = v >> 4, pxg = (v & 15) * 4;
        f32x4 f = *(const f32x4*)&xs[ch * 64 + pxg];
        u16x4 p;
        p.x0 = f2b(f[0]); p.x1 = f2b(f[1]); p.x2 = f2b(f[2]); p.x3 = f2b(f[3]);
        *(u16x4*)&xb[(size_t)ch * RS + pxg] = p;
    }
}

// ---------------------------------------------------------------------------
// Fused context model (unchanged, verified).
// ---------------------------------------------------------------------------
__global__ __launch_bounds__(256)
void trik(float* __restrict__ y, const float* __restrict__ noise,
          const float* __restrict__ H, const float* __restrict__ mean,
          const float* __restrict__ scale, float* __restrict__ lik)
{
    __shared__ float h[64 * 65];
    const int c = blockIdx.x;
    const int bt = blockIdx.y;
    const int tid = threadIdx.x;
    const int lane = tid & 63;
    const int wv = tid >> 6;

    const float* Hc = H + (size_t)c * 4096;
    for (int idx = tid; idx < 4096; idx += 256) {
        const int i = idx >> 6, j = idx & 63;
        h[i * 65 + j] = Hc[idx];
    }
    __syncthreads();

    const int b = bt * 4 + wv;
    const size_t base = ((size_t)b * 320 + c) * 64 + lane;
    const float* hrow = &h[lane * 65];

    const float yv = y[base];
    float ws = 0.f;
#pragma unroll 8
    for (int j = 0; j < 64; ++j) {
        const float yj = __shfl(yv, j, 64);
        const float hv = (j < lane) ? hrow[j] : 0.f;
        ws = fmaf(hv, yj, ws);
    }
    const float wh = yv - ws + noise[base];

    const float mn = mean[c * 64 + lane];
    const float sc = fmaxf(scale[c * 64 + lane], 0.11f);
    const float vv = fabsf(wh - mn);
    const float cst = -0.70710678118654752f;
    const float upper = 0.5f * erfcf(cst * (0.5f - vv) / sc);
    const float lower = 0.5f * erfcf(cst * (-0.5f - vv) / sc);
    lik[base] = fmaxf(upper - lower, 1e-9f);

    float acc = wh;
#pragma unroll 8
    for (int j = 0; j < 64; ++j) {
        const float yj = __shfl(acc, j, 64);
        const float hv = (j < lane) ? hrow[j] : 0.f;
        acc = fmaf(hv, yj, acc);
    }
    y[base] = acc;
}

// ---------------------------------------------------------------------------
extern "C" void kernel_launch(void* const* d_in, const int* in_sizes, int n_in,
                              void* d_out, int out_size, void* d_ws, size_t ws_size,
                              hipStream_t stream)
{
    (void)in_sizes; (void)n_in; (void)out_size; (void)ws_size;

    const float* x      = (const float*)d_in[0];
    const float* noise  = (const float*)d_in[1];
    const float* w1     = (const float*)d_in[2];
    const float* b1     = (const float*)d_in[3];
    const float* beta1  = (const float*)d_in[4];
    const float* gamma1 = (const float*)d_in[5];
    const float* w2     = (const float*)d_in[6];
    const float* b2     = (const float*)d_in[7];
    const float* beta2  = (const float*)d_in[8];
    const float* gamma2 = (const float*)d_in[9];
    const float* w3     = (const float*)d_in[10];
    const float* b3     = (const float*)d_in[11];
    const float* dw1    = (const float*)d_in[12];
    const float* db1    = (const float*)d_in[13];
    const float* ibeta1 = (const float*)d_in[14];
    const float* igamma1= (const float*)d_in[15];
    const float* dw2    = (const float*)d_in[16];
    const float* db2    = (const float*)d_in[17];
    const float* ibeta2 = (const float*)d_in[18];
    const float* igamma2= (const float*)d_in[19];
    const float* dw3    = (const float*)d_in[20];
    const float* db3    = (const float*)d_in[21];
    const float* mean   = (const float*)d_in[22];
    const float* scale  = (const float*)d_in[23];
    const float* H      = (const float*)d_in[24];

    float* outp = (float*)d_out;
    float* xhat = outp;                                   // [1024,2,32,32]
    float* lik  = outp + (size_t)1024 * 2 * 32 * 32;      // [1024,320,64]

    // workspace layout (peak 217.6 MB):
    //   [0, 134.2M)      a1 bf16 -> y f32 -> d2 bf16 (quadrant-planar)
    //   [134.2M, 201.3M) a2 f32 -> d1 f32
    //   [201.3M, 217.6M) repacked weights (live whole call)
    char* ws = (char*)d_ws;
    u16*   a1  = (u16*)ws;
    float* a2  = (float*)(ws + 134217728);
    float* y   = (float*)ws;
    float* d1  = (float*)(ws + 134217728);
    u16*   d2  = (u16*)ws;
    u16*   Ac2 = (u16*)(ws + 201326592);
    u16*   Ac3 = (u16*)(ws + 204603392);
    u16*   Ad1 = (u16*)(ws + 208699392);
    u16*   Ad2 = (u16*)(ws + 212795392);
    float* W3r = (float*)(ws + 217513984);

    // ---- weight repacks (paired u32 stores) ----
    rk_fwd<256, 256><<<3200, 256, 0, stream>>>(w2, Ac2);
    rk_fwd<256, 320><<<4000, 256, 0, stream>>>(w3, Ac3);
    rk_d1<<<4000, 256, 0, stream>>>(dw1, Ad1);
    rk_d2<<<4608, 256, 0, stream>>>(dw2, Ad2);
    rk_d3<<<128, 256, 0, stream>>>(dw3, W3r);

    // ---- analysis ----
    conv5k<2, 256, 32, 32, 2, 2, 16><<<dim3(1024, 16), 256, 0, stream>>>(x, w1, b1, a1);
    gdnk16<false, false><<<dim3(1024, 4), 256, 0, stream>>>(a1, beta1, gamma1);
    mconv<256, 256, 2, 4, u16><<<1024, 256, 0, stream>>>(a1, Ac2, b2, a2);
    gdnk<float, 64, false><<<dim3(1024, 1), 256, 0, stream>>>(a2, beta2, gamma2);
    mconv<256, 320, 1, 5, float><<<1024, 256, 0, stream>>>(a2, Ac3, b3, y);

    // ---- context model ----
    trik<<<dim3(320, 256), 256, 0, stream>>>(y, noise, H, mean, scale, lik);

    // ---- synthesis ----
    mconv<320, 256, 1, 4, float><<<1024, 256, 0, stream>>>(y, Ad1, db1, d1);
    gdnk<float, 64, true><<<dim3(1024, 1), 256, 0, stream>>>(d1, ibeta1, igamma1);
    mdeconv2<<<1024, 256, 0, stream>>>(d1, Ad2, db2, d2);
    gdnk16<true, true><<<dim3(1024, 4), 256, 0, stream>>>(d2, ibeta2, igamma2);
    dec3k<<<1024, 256, 0, stream>>>(d2, W3r, db3, xhat);
}